// Round 16
// baseline (146.495 us; speedup 1.0000x reference)
//
#include <hip/hip_runtime.h>
#include <hip/hip_bf16.h>
#include <math.h>

// Problem constants
#define BB 256
#define DD 512
#define LL 196
#define NN 1024
#define MM 512
#define KK 10000

// ---- output layout (float offsets) ----
#define OUT_PY 0
#define OUT_HN ((size_t)2560000)
#define OUT_CN ((size_t)2822144)
#define OUT_AL ((size_t)3084288)

// ---- workspace layout (float-word offsets) ----
#define OFF_PE     ((size_t)0)          // B*16*196 = 802816
#define OFF_BETA   ((size_t)802816)     // 256
#define OFF_EMB    ((size_t)803072)     // B*512 fp32 = 131072
// contiguous atomic accumulators (zeroed each run by P1 zero-role):
#define OFF_ACC    ((size_t)934144)
#define OFF_EMBP1  (OFF_ACC)                      // B*512   = 131072
#define OFF_GATESP1 (OFF_ACC + 131072)            // B*4096  = 1048576
#define OFF_DP1    (OFF_ACC + 1179648)            // B*512   = 131072
#define ACC_FLOATS 1310720
// bf16 buffers (sizes in float-words = shorts/2)
#define OFF_EWB    ((size_t)14565632)
#define OFF_WIHB   ((size_t)17125632)
#define OFF_WHHB   ((size_t)21319936)
#define OFF_LHB    ((size_t)23417088)
#define OFF_LZB    ((size_t)23679232)
#define OFF_LOB    ((size_t)23810304)
#define OFF_INPB   ((size_t)26370304)
#define OFF_HB     ((size_t)27650304)
#define OFF_ZB     ((size_t)27781376)
#define OFF_EMBB   ((size_t)27846912)
#define OFF_DEEPB  ((size_t)27912448)
#define OFF_HNB    ((size_t)27977984)

typedef __attribute__((ext_vector_type(8))) short short8v;
typedef __attribute__((ext_vector_type(4))) float f32x4;

__device__ __forceinline__ unsigned short f2bf(float f) {
    unsigned int u = __builtin_bit_cast(unsigned int, f);
    u += 0x7fffu + ((u >> 16) & 1u);            // RNE
    return (unsigned short)(u >> 16);
}

__device__ __forceinline__ void gl_lds16(const float* g, float* l) {
    __builtin_amdgcn_global_load_lds(
        (const __attribute__((address_space(1))) void*)g,
        (__attribute__((address_space(3))) void*)l, 16, 0, 0);
}

__device__ __forceinline__ void cvt_body(int lb, const float* __restrict__ src,
                                         unsigned short* __restrict__ dst, int n,
                                         int t) {
#pragma unroll
    for (int i = 0; i < 8; ++i) {
        const size_t e = (size_t)lb * 16384 + (size_t)i * 2048 + (size_t)t * 8;
        if (e + 8 <= (size_t)n) {
            const float4 x = *(const float4*)(src + e);
            const float4 y = *(const float4*)(src + e + 4);
            short8v v;
            v[0] = (short)f2bf(x.x); v[1] = (short)f2bf(x.y);
            v[2] = (short)f2bf(x.z); v[3] = (short)f2bf(x.w);
            v[4] = (short)f2bf(y.x); v[5] = (short)f2bf(y.y);
            v[6] = (short)f2bf(y.z); v[7] = (short)f2bf(y.w);
            *(short8v*)(dst + e) = v;
        }
    }
}

__device__ __forceinline__ short8v stage8b(const unsigned short* __restrict__ p,
                                           bool ok, int kbase, int Ktot) {
    if (ok && (kbase + 7 < Ktot)) return *(const short8v*)(p + kbase);
    short8v v;
#pragma unroll
    for (int i = 0; i < 8; ++i) {
        const int k = kbase + i;
        v[i] = (ok && k < Ktot) ? (short)p[k] : (short)0;
    }
    return v;
}

struct GSrc { const unsigned short* A; int lda; const unsigned short* B; int ldb; int ktn; int K; };

// Dual-source TN GEMM body, pure bf16 inputs, 64x64 tile, BK=64, 256 threads.
// atomicOut: accumulate into C via atomicAdd (no slice offset), for split-K.
__device__ __forceinline__ void gemm_body(
    const int bx, const int by, const int bz, const int rowBlocks,
    const GSrc s1, const GSrc s2,
    float* __restrict__ C, const int ldc, const int Ncols,
    const int ktPerSplit, const float* __restrict__ bias, const int atomicOut,
    short (*As)[64][72], short (*Bs)[64][72])
{
    const int t = threadIdx.x;
    const int row0 = bx * 64;
    const int col0 = by * 64;
    const int ktTot = s1.ktn + s2.ktn;
    const int kt0 = bz * ktPerSplit;
    const int nk = min(ktTot, kt0 + ktPerSplit) - kt0;

    const int sr = t >> 2;
    const int sk = (t & 3) << 4;
    const int bc = col0 + sr;
    const bool bok = (bc < Ncols);
    const unsigned short* aP1 = s1.A + (size_t)(row0 + sr) * s1.lda;
    const unsigned short* bP1 = s1.B + (size_t)(bok ? bc : 0) * s1.ldb;
    const unsigned short* aP2 = s2.A ? (s2.A + (size_t)(row0 + sr) * s2.lda) : aP1;
    const unsigned short* bP2 = s2.A ? (s2.B + (size_t)(bok ? bc : 0) * s2.ldb) : bP1;

    const int l = t & 63, w = t >> 6;
    const int wrow = (w >> 1) * 32, wcol = (w & 1) * 32;
    const int lr = l & 15, g = l >> 4, g8 = g * 8;

    f32x4 acc[2][2] = {};

    short8v sa0, sa1, sb0, sb1;
    {
        const int ktg = kt0;
        const unsigned short* aR; const unsigned short* bR; int kk, Kt;
        if (ktg < s1.ktn) { aR = aP1; bR = bP1; kk = (ktg << 6) + sk; Kt = s1.K; }
        else              { aR = aP2; bR = bP2; kk = ((ktg - s1.ktn) << 6) + sk; Kt = s2.K; }
        sa0 = stage8b(aR, true, kk, Kt);  sa1 = stage8b(aR, true, kk + 8, Kt);
        sb0 = stage8b(bR, bok,  kk, Kt);  sb1 = stage8b(bR, bok,  kk + 8, Kt);
    }
    *(short8v*)&As[0][sr][sk] = sa0; *(short8v*)&As[0][sr][sk + 8] = sa1;
    *(short8v*)&Bs[0][sr][sk] = sb0; *(short8v*)&Bs[0][sr][sk + 8] = sb1;
    __syncthreads();

    int cur = 0;
    for (int kt = 0; kt < nk; ++kt) {
        const bool more = (kt + 1 < nk);
        if (more) {
            const int ktg = kt0 + kt + 1;
            const unsigned short* aR; const unsigned short* bR; int kk, Kt;
            if (ktg < s1.ktn) { aR = aP1; bR = bP1; kk = (ktg << 6) + sk; Kt = s1.K; }
            else              { aR = aP2; bR = bP2; kk = ((ktg - s1.ktn) << 6) + sk; Kt = s2.K; }
            sa0 = stage8b(aR, true, kk, Kt);  sa1 = stage8b(aR, true, kk + 8, Kt);
            sb0 = stage8b(bR, bok,  kk, Kt);  sb1 = stage8b(bR, bok,  kk + 8, Kt);
        }
#pragma unroll
        for (int ks = 0; ks < 2; ++ks) {
            const int ko = ks * 32 + g8;
            short8v a0 = *(const short8v*)&As[cur][wrow + lr][ko];
            short8v a1 = *(const short8v*)&As[cur][wrow + 16 + lr][ko];
            short8v b0 = *(const short8v*)&Bs[cur][wcol + lr][ko];
            short8v b1 = *(const short8v*)&Bs[cur][wcol + 16 + lr][ko];
            acc[0][0] = __builtin_amdgcn_mfma_f32_16x16x32_bf16(a0, b0, acc[0][0], 0, 0, 0);
            acc[0][1] = __builtin_amdgcn_mfma_f32_16x16x32_bf16(a0, b1, acc[0][1], 0, 0, 0);
            acc[1][0] = __builtin_amdgcn_mfma_f32_16x16x32_bf16(a1, b0, acc[1][0], 0, 0, 0);
            acc[1][1] = __builtin_amdgcn_mfma_f32_16x16x32_bf16(a1, b1, acc[1][1], 0, 0, 0);
        }
        if (more) {
            *(short8v*)&As[cur ^ 1][sr][sk] = sa0;
            *(short8v*)&As[cur ^ 1][sr][sk + 8] = sa1;
            *(short8v*)&Bs[cur ^ 1][sr][sk] = sb0;
            *(short8v*)&Bs[cur ^ 1][sr][sk + 8] = sb1;
        }
        __syncthreads();
        cur ^= 1;
    }

    float* Cp = C + (atomicOut ? (size_t)0
                               : (size_t)bz * ((size_t)rowBlocks * 64) * ldc);
#pragma unroll
    for (int m = 0; m < 2; ++m)
#pragma unroll
        for (int n = 0; n < 2; ++n)
#pragma unroll
            for (int j = 0; j < 4; ++j) {
                const int r = row0 + wrow + m * 16 + g * 4 + j;
                const int c = col0 + wcol + n * 16 + lr;
                if (c < Ncols) {
                    float v = acc[m][n][j];
                    if (bias) v += bias[c];
                    if (atomicOut) atomicAdd(&Cp[(size_t)r * ldc + c], v);
                    else           Cp[(size_t)r * ldc + c] = v;
                }
            }
}

struct MegaP {
    const float *a_i, *inp, *h, *c_prev, *f_att_w, *f_att_b, *gate_w, *gate_b,
                *E_w, *E_b, *W_ih, *W_hh, *b_ih, *b_hh, *Lh_w, *Lh_b, *Lz_w,
                *Lz_b, *Lo_w, *Lo_b;
    float *alpha, *py, *hnout, *cnout;
    float *pe, *beta, *emb, *embp1, *gatesp1, *dp1, *accbase;
    unsigned short *ewb, *wihb, *whhb, *lhb, *lzb, *lob, *inpb, *hb, *zb,
                   *embb, *deepb, *hnb;
};

// ---- phase unit bodies ----

// P1: att_e slabs (4096) + cvt{E_w:313, inp:157, h:16} + zero-acc (320)
__device__ __forceinline__ void unit_p1(int u, int t, unsigned char* smem, const MegaP& p)
{
    if (u < 4096) {
        float* slab = (float*)smem;                  // 6280 floats
        const int b = u >> 4, ch = u & 15;
        const int w = t >> 6, lane = t & 63;
        const float* gbase = p.a_i + ((size_t)b * DD + ch * 32) * LL;
#pragma unroll
        for (int k = 0; k < 7; ++k) {
            const int cw = k * 256 + w * 64;
            if (cw + lane < 1568)
                gl_lds16(gbase + (size_t)(cw + lane) * 4, slab + (size_t)cw * 4);
        }
        if (t < 8) slab[6272 + t] = 0.f;
        asm volatile("s_waitcnt vmcnt(0)" ::: "memory");
        __syncthreads();
        if (t < LL) {
            const float* wp = p.f_att_w + ch * 32;
            float e = 0.f;
#pragma unroll
            for (int d = 0; d < 32; ++d) e += slab[d * LL + t] * wp[d];
            p.pe[((size_t)b * 16 + ch) * LL + t] = e;
        }
    } else if (u < 4582) {
        int lb = u - 4096;
        if      (lb < 313) cvt_body(lb, p.E_w, p.ewb, 5120000, t);
        else if (lb < 470) cvt_body(lb - 313, p.inp, p.inpb, 2560000, t);
        else               cvt_body(lb - 470, p.h, p.hb, 262144, t);
    } else {
        // zero the atomic accumulators: 320 blocks x 4096 floats
        const int lb = u - 4582;
        float* dst = p.accbase + (size_t)lb * 4096 + (size_t)t * 16;
        const float4 zz = make_float4(0.f, 0.f, 0.f, 0.f);
#pragma unroll
        for (int i = 0; i < 4; ++i) *(float4*)(dst + i * 4) = zz;
    }
}

// P2: softmax (256) + emb GEMM (512, atomic) + cvt{W_ih:512, W_hh:256}
__device__ __forceinline__ void unit_p2(int u, int t, unsigned char* smem, const MegaP& p)
{
    if (u < 256) {
        const int b = u;
        float* red  = (float*)smem;
        float* red2 = red + 256;
        const float4 h4 = *(const float4*)(p.h + (size_t)b * NN + t * 4);
        const float4 w4 = *(const float4*)(p.f_att_w + DD + t * 4);
        const float4 g4 = *(const float4*)(p.gate_w + t * 4);
        float hd = h4.x * w4.x + h4.y * w4.y + h4.z * w4.z + h4.w * w4.w;
        float gd = h4.x * g4.x + h4.y * g4.y + h4.z * g4.z + h4.w * g4.w;
        red[t] = hd; red2[t] = gd;
        __syncthreads();
        for (int s = 128; s > 0; s >>= 1) {
            if (t < s) { red[t] += red[t + s]; red2[t] += red2[t + s]; }
            __syncthreads();
        }
        const float hdot = red[0];
        const float gdot = red2[0];
        __syncthreads();
        float e = -3.4e38f;
        if (t < LL) {
            const float* pp = p.pe + (size_t)b * 16 * LL + t;
            e = hdot + p.f_att_b[0];
#pragma unroll
            for (int ch = 0; ch < 16; ++ch) e += pp[ch * LL];
        }
        red[t] = e;
        __syncthreads();
        for (int s = 128; s > 0; s >>= 1) {
            if (t < s) red[t] = fmaxf(red[t], red[t + s]);
            __syncthreads();
        }
        const float mx = red[0];
        __syncthreads();
        const float ex = (t < LL) ? expf(e - mx) : 0.f;
        red[t] = ex;
        __syncthreads();
        for (int s = 128; s > 0; s >>= 1) {
            if (t < s) red[t] += red[t + s];
            __syncthreads();
        }
        const float inv = 1.f / red[0];
        if (t < LL) p.alpha[(size_t)b * LL + t] = ex * inv;
        if (t == 0) p.beta[b] = 1.f / (1.f + expf(-(gdot + p.gate_b[0])));
    } else if (u < 768) {
        short (*As)[64][72] = (short (*)[64][72])smem;
        short (*Bs)[64][72] = (short (*)[64][72])(smem + 18432);
        const int i = u - 256;                        // 512 = 4*8*16
        GSrc s1 = {p.inpb, KK, p.ewb, KK, 157, KK};
        GSrc s2 = {nullptr, 0, nullptr, 0, 0, 0};
        gemm_body(i & 3, (i >> 2) & 7, i >> 5, 4, s1, s2,
                  p.embp1, MM, MM, 10, nullptr, 1, As, Bs);
    } else {
        int lb = u - 768;
        if (lb < 512) cvt_body(lb, p.W_ih, p.wihb, 8388608, t);
        else          cvt_body(lb - 512, p.W_hh, p.whhb, 4194304, t);
    }
}

// P3: att_z slabs (4096) + emb finalize (512) + cvt{Lo:313,Lh:32,Lz:16}
__device__ __forceinline__ void unit_p3(int u, int t, unsigned char* smem, const MegaP& p)
{
    if (u < 4096) {
        float* slab = (float*)smem;
        float* al   = (float*)(smem + 25120);
        const int b = u >> 4, ch = u & 15;
        const int w = t >> 6, lane = t & 63;
        const float* gbase = p.a_i + ((size_t)b * DD + ch * 32) * LL;
#pragma unroll
        for (int k = 0; k < 7; ++k) {
            const int cw = k * 256 + w * 64;
            if (cw + lane < 1568)
                gl_lds16(gbase + (size_t)(cw + lane) * 4, slab + (size_t)cw * 4);
        }
        if (t < 200) al[t] = (t < LL) ? p.alpha[(size_t)b * LL + t] : 0.f;
        if (t < 8) slab[6272 + t] = 0.f;
        asm volatile("s_waitcnt vmcnt(0)" ::: "memory");
        __syncthreads();
        const int r = t >> 3, q = t & 7;
        const float* rowp = slab + r * LL + q * 25;
        const float* alq  = al + q * 25;
        float s = 0.f;
#pragma unroll
        for (int j = 0; j < 25; ++j) s += rowp[j] * alq[j];
        s += __shfl_xor(s, 1, 64);
        s += __shfl_xor(s, 2, 64);
        s += __shfl_xor(s, 4, 64);
        if (q == 0) p.zb[(size_t)b * DD + ch * 32 + r] = f2bf(p.beta[b] * s);
    } else if (u < 4608) {
        const int idx = (u - 4096) * 256 + t;         // < B*512
        const int j = idx & 511;
        const float v = p.E_b[j] + p.embp1[idx];
        p.emb[idx] = v;
        p.embb[idx] = f2bf(v);
    } else {
        int lb = u - 4608;
        if      (lb < 313) cvt_body(lb, p.Lo_w, p.lob, 5120000, t);
        else if (lb < 345) cvt_body(lb - 313, p.Lh_w, p.lhb, 524288, t);
        else               cvt_body(lb - 345, p.Lz_w, p.lzb, 262144, t);
    }
}

// P4: gates_h (512) + gates_e (512) + gates_z (512) + lz (256) — all atomic
__device__ __forceinline__ void unit_p4(int u, int t, unsigned char* smem, const MegaP& p)
{
    short (*As)[64][72] = (short (*)[64][72])smem;
    short (*Bs)[64][72] = (short (*)[64][72])(smem + 18432);
    if (u < 512) {                                    // 4*64*2, nk=16
        GSrc s1 = {p.hb, NN, p.wihb + 512, 2048, 16, NN};
        GSrc s2 = {p.hb, NN, p.whhb, NN, 16, NN};
        gemm_body(u & 3, (u >> 2) & 63, u >> 8, 4, s1, s2,
                  p.gatesp1, 4096, 4096, 16, nullptr, 1, As, Bs);
    } else if (u < 1024) {                            // 4*64*2, nk=4
        const int i = u - 512;
        GSrc s1 = {p.embb, MM, p.wihb, 2048, 8, MM};
        GSrc s2 = {nullptr, 0, nullptr, 0, 0, 0};
        gemm_body(i & 3, (i >> 2) & 63, i >> 8, 4, s1, s2,
                  p.gatesp1, 4096, 4096, 4, nullptr, 1, As, Bs);
    } else if (u < 1536) {
        const int i = u - 1024;
        GSrc s1 = {p.zb, DD, p.wihb + 1536, 2048, 8, DD};
        GSrc s2 = {nullptr, 0, nullptr, 0, 0, 0};
        gemm_body(i & 3, (i >> 2) & 63, i >> 8, 4, s1, s2,
                  p.gatesp1, 4096, 4096, 4, nullptr, 1, As, Bs);
    } else {
        const int i = u - 1536;                       // 256 = 4*8*8, nk=1
        GSrc s1 = {p.zb, DD, p.lzb, DD, 8, DD};
        GSrc s2 = {nullptr, 0, nullptr, 0, 0, 0};
        gemm_body(i & 3, (i >> 2) & 7, i >> 5, 4, s1, s2,
                  p.dp1, MM, MM, 1, nullptr, 1, As, Bs);
    }
}

// P5: LSTM cell (single accumulated gates buffer)
__device__ __forceinline__ void unit_p5(int u, int t, const MegaP& p)
{
    const int idx = u * 256 + t;                      // < B*1024
    const int b = idx >> 10, n = idx & 1023;
    float g[4];
#pragma unroll
    for (int gi = 0; gi < 4; ++gi) {
        const int col = gi * 1024 + n;
        g[gi] = p.b_ih[col] + p.b_hh[col] + p.gatesp1[(size_t)b * 4096 + col];
    }
    const float si = 1.f / (1.f + expf(-g[0]));
    const float sf = 1.f / (1.f + expf(-g[1]));
    const float so = 1.f / (1.f + expf(-g[3]));
    const float tg = tanhf(g[2]);
    const float c = p.c_prev[idx];
    const float cnv = sf * c + si * tg;
    const float hnv = so * tanhf(cnv);
    p.cnout[idx] = cnv;
    p.hnout[idx] = hnv;
    p.hnb[idx] = f2bf(hnv);
}

// P6: lh GEMM (512, atomic into dp1)
__device__ __forceinline__ void unit_p6(int u, int t, unsigned char* smem, const MegaP& p)
{
    short (*As)[64][72] = (short (*)[64][72])smem;
    short (*Bs)[64][72] = (short (*)[64][72])(smem + 18432);
    GSrc s1 = {p.hnb, NN, p.lhb, NN, 16, NN};
    GSrc s2 = {nullptr, 0, nullptr, 0, 0, 0};
    gemm_body(u & 3, (u >> 2) & 7, u >> 5, 4, s1, s2,
              p.dp1, MM, MM, 1, nullptr, 1, As, Bs);
}

// P7: deep (single accumulated dp buffer)
__device__ __forceinline__ void unit_p7(int u, int t, const MegaP& p)
{
    const int idx = u * 256 + t;                      // < B*512
    const int j = idx & 511;
    const float v = p.emb[idx] + p.Lh_b[j] + p.Lz_b[j] + p.dp1[idx];
    p.deepb[idx] = f2bf(v);
}

// P8: p_yt GEMM (628)
__device__ __forceinline__ void unit_p8(int u, int t, unsigned char* smem, const MegaP& p)
{
    short (*As)[64][72] = (short (*)[64][72])smem;
    short (*Bs)[64][72] = (short (*)[64][72])(smem + 18432);
    GSrc s1 = {p.deepb, MM, p.lob, MM, 8, MM};
    GSrc s2 = {nullptr, 0, nullptr, 0, 0, 0};
    gemm_body(u & 3, u >> 2, 0, 4, s1, s2,
              p.py, KK, KK, 8, p.Lo_b, 0, As, Bs);
}

// ==== one kernel per phase; LDS right-sized per kernel ====
__global__ __launch_bounds__(256) void gk_p1(MegaP p) {
    __shared__ __align__(16) unsigned char smem[25120];   // slab only -> 6 blk/CU
    unit_p1(blockIdx.x, threadIdx.x, smem, p);
}
__global__ __launch_bounds__(256) void gk_p2(MegaP p) {
    __shared__ __align__(16) unsigned char smem[36864];
    unit_p2(blockIdx.x, threadIdx.x, smem, p);
}
__global__ __launch_bounds__(256) void gk_p3(MegaP p) {
    __shared__ __align__(16) unsigned char smem[25920];   // slab + alpha
    unit_p3(blockIdx.x, threadIdx.x, smem, p);
}
__global__ __launch_bounds__(256) void gk_p4(MegaP p) {
    __shared__ __align__(16) unsigned char smem[36864];
    unit_p4(blockIdx.x, threadIdx.x, smem, p);
}
__global__ __launch_bounds__(256) void gk_p5(MegaP p) {
    unit_p5(blockIdx.x, threadIdx.x, p);
}
__global__ __launch_bounds__(256) void gk_p6(MegaP p) {
    __shared__ __align__(16) unsigned char smem[36864];
    unit_p6(blockIdx.x, threadIdx.x, smem, p);
}
__global__ __launch_bounds__(256) void gk_p7(MegaP p) {
    unit_p7(blockIdx.x, threadIdx.x, p);
}
__global__ __launch_bounds__(256) void gk_p8(MegaP p) {
    __shared__ __align__(16) unsigned char smem[36864];
    unit_p8(blockIdx.x, threadIdx.x, smem, p);
}

extern "C" void kernel_launch(void* const* d_in, const int* in_sizes, int n_in,
                              void* d_out, int out_size, void* d_ws, size_t ws_size,
                              hipStream_t stream)
{
    float* out = (float*)d_out;
    float* ws  = (float*)d_ws;

    MegaP p;
    p.a_i     = (const float*)d_in[0];
    p.inp     = (const float*)d_in[1];
    p.h       = (const float*)d_in[2];
    p.c_prev  = (const float*)d_in[3];
    p.f_att_w = (const float*)d_in[4];
    p.f_att_b = (const float*)d_in[5];
    p.gate_w  = (const float*)d_in[6];
    p.gate_b  = (const float*)d_in[7];
    p.E_w     = (const float*)d_in[8];
    p.E_b     = (const float*)d_in[9];
    p.W_ih    = (const float*)d_in[10];
    p.W_hh    = (const float*)d_in[11];
    p.b_ih    = (const float*)d_in[12];
    p.b_hh    = (const float*)d_in[13];
    p.Lh_w    = (const float*)d_in[14];
    p.Lh_b    = (const float*)d_in[15];
    p.Lz_w    = (const float*)d_in[16];
    p.Lz_b    = (const float*)d_in[17];
    p.Lo_w    = (const float*)d_in[18];
    p.Lo_b    = (const float*)d_in[19];
    p.alpha   = out + OUT_AL;
    p.py      = out + OUT_PY;
    p.hnout   = out + OUT_HN;
    p.cnout   = out + OUT_CN;
    p.pe      = ws + OFF_PE;
    p.beta    = ws + OFF_BETA;
    p.emb     = ws + OFF_EMB;
    p.embp1   = ws + OFF_EMBP1;
    p.gatesp1 = ws + OFF_GATESP1;
    p.dp1     = ws + OFF_DP1;
    p.accbase = ws + OFF_ACC;
    p.ewb     = (unsigned short*)(ws + OFF_EWB);
    p.wihb    = (unsigned short*)(ws + OFF_WIHB);
    p.whhb    = (unsigned short*)(ws + OFF_WHHB);
    p.lhb     = (unsigned short*)(ws + OFF_LHB);
    p.lzb     = (unsigned short*)(ws + OFF_LZB);
    p.lob     = (unsigned short*)(ws + OFF_LOB);
    p.inpb    = (unsigned short*)(ws + OFF_INPB);
    p.hb      = (unsigned short*)(ws + OFF_HB);
    p.zb      = (unsigned short*)(ws + OFF_ZB);
    p.embb    = (unsigned short*)(ws + OFF_EMBB);
    p.deepb   = (unsigned short*)(ws + OFF_DEEPB);
    p.hnb     = (unsigned short*)(ws + OFF_HNB);

    gk_p1<<<4902, 256, 0, stream>>>(p);   // att_e + cvt1 + zero-acc
    gk_p2<<<1536, 256, 0, stream>>>(p);   // softmax + emb GEMM + cvt2
    gk_p3<<<4969, 256, 0, stream>>>(p);   // att_z + emb finalize + cvt3
    gk_p4<<<1792, 256, 0, stream>>>(p);   // gates GEMMs + lz (atomic)
    gk_p5<<<1024, 256, 0, stream>>>(p);   // LSTM cell
    gk_p6<<<512, 256, 0, stream>>>(p);    // lh GEMM (atomic)
    gk_p7<<<512, 256, 0, stream>>>(p);    // deep
    gk_p8<<<628, 256, 0, stream>>>(p);    // p_yt GEMM
}

// Round 17
// 137.557 us; speedup vs baseline: 1.0650x; 1.0650x over previous
//
#include <hip/hip_runtime.h>
#include <hip/hip_bf16.h>
#include <math.h>

// Problem constants
#define BB 256
#define DD 512
#define LL 196
#define NN 1024
#define MM 512
#define KK 10000

// ---- output layout (float offsets) ----
#define OUT_PY 0
#define OUT_HN ((size_t)2560000)
#define OUT_CN ((size_t)2822144)
#define OUT_AL ((size_t)3084288)

// ---- workspace layout (float-word offsets) ----
#define OFF_PE     ((size_t)0)          // B*16*196 = 802816
#define OFF_BETA   ((size_t)802816)     // 256
#define OFF_EMB    ((size_t)803072)     // B*512 fp32 = 131072
#define OFF_EMBP   ((size_t)934144)     // 16 * B*512 = 2097152
#define OFF_GATESP ((size_t)3031296)    // 8 * B*4096 = 8388608
#define OFF_DP     ((size_t)11419904)   // 24 * B*512 = 3145728
// bf16 buffers (sizes in float-words = shorts/2)
#define OFF_EWB    ((size_t)14565632)   // 512*10000  -> 2560000
#define OFF_WIHB   ((size_t)17125632)   // 4096*2048  -> 4194304
#define OFF_WHHB   ((size_t)21319936)   // 4096*1024  -> 2097152
#define OFF_LHB    ((size_t)23417088)   // 512*1024   -> 262144
#define OFF_LZB    ((size_t)23679232)   // 512*512    -> 131072
#define OFF_LOB    ((size_t)23810304)   // 10000*512  -> 2560000
#define OFF_INPB   ((size_t)26370304)   // 256*10000  -> 1280000
#define OFF_HB     ((size_t)27650304)   // 256*1024   -> 131072
#define OFF_ZB     ((size_t)27781376)   // 256*512    -> 65536
#define OFF_EMBB   ((size_t)27846912)   // 256*512    -> 65536
#define OFF_DEEPB  ((size_t)27912448)   // 256*512    -> 65536
#define OFF_HNB    ((size_t)27977984)   // 256*1024   -> 131072

typedef __attribute__((ext_vector_type(8))) short short8v;
typedef __attribute__((ext_vector_type(4))) float f32x4;

__device__ __forceinline__ unsigned short f2bf(float f) {
    unsigned int u = __builtin_bit_cast(unsigned int, f);
    u += 0x7fffu + ((u >> 16) & 1u);            // RNE
    return (unsigned short)(u >> 16);
}

__device__ __forceinline__ void gl_lds16(const float* g, float* l) {
    __builtin_amdgcn_global_load_lds(
        (const __attribute__((address_space(1))) void*)g,
        (__attribute__((address_space(3))) void*)l, 16, 0, 0);
}

__device__ __forceinline__ void cvt_body(int lb, const float* __restrict__ src,
                                         unsigned short* __restrict__ dst, int n,
                                         int t) {
#pragma unroll
    for (int i = 0; i < 8; ++i) {
        const size_t e = (size_t)lb * 16384 + (size_t)i * 2048 + (size_t)t * 8;
        if (e + 8 <= (size_t)n) {
            const float4 x = *(const float4*)(src + e);
            const float4 y = *(const float4*)(src + e + 4);
            short8v v;
            v[0] = (short)f2bf(x.x); v[1] = (short)f2bf(x.y);
            v[2] = (short)f2bf(x.z); v[3] = (short)f2bf(x.w);
            v[4] = (short)f2bf(y.x); v[5] = (short)f2bf(y.y);
            v[6] = (short)f2bf(y.z); v[7] = (short)f2bf(y.w);
            *(short8v*)(dst + e) = v;
        }
    }
}

__device__ __forceinline__ short8v stage8b(const unsigned short* __restrict__ p,
                                           bool ok, int kbase, int Ktot) {
    if (ok && (kbase + 7 < Ktot)) return *(const short8v*)(p + kbase);
    short8v v;
#pragma unroll
    for (int i = 0; i < 8; ++i) {
        const int k = kbase + i;
        v[i] = (ok && k < Ktot) ? (short)p[k] : (short)0;
    }
    return v;
}

struct GSrc { const unsigned short* A; int lda; const unsigned short* B; int ldb; int ktn; int K; };

// Dual-source TN GEMM body, pure bf16 inputs, 64x64 tile, BK=64, 256 threads.
__device__ __forceinline__ void gemm_body(
    const int bx, const int by, const int bz, const int rowBlocks,
    const GSrc s1, const GSrc s2,
    float* __restrict__ C, const int ldc, const int Ncols,
    const int ktPerSplit, const float* __restrict__ bias,
    short (*As)[64][72], short (*Bs)[64][72])
{
    const int t = threadIdx.x;
    const int row0 = bx * 64;
    const int col0 = by * 64;
    const int ktTot = s1.ktn + s2.ktn;
    const int kt0 = bz * ktPerSplit;
    const int nk = min(ktTot, kt0 + ktPerSplit) - kt0;

    const int sr = t >> 2;
    const int sk = (t & 3) << 4;
    const int bc = col0 + sr;
    const bool bok = (bc < Ncols);
    const unsigned short* aP1 = s1.A + (size_t)(row0 + sr) * s1.lda;
    const unsigned short* bP1 = s1.B + (size_t)(bok ? bc : 0) * s1.ldb;
    const unsigned short* aP2 = s2.A ? (s2.A + (size_t)(row0 + sr) * s2.lda) : aP1;
    const unsigned short* bP2 = s2.A ? (s2.B + (size_t)(bok ? bc : 0) * s2.ldb) : bP1;

    const int l = t & 63, w = t >> 6;
    const int wrow = (w >> 1) * 32, wcol = (w & 1) * 32;
    const int lr = l & 15, g = l >> 4, g8 = g * 8;

    f32x4 acc[2][2] = {};

    short8v sa0, sa1, sb0, sb1;
    {
        const int ktg = kt0;
        const unsigned short* aR; const unsigned short* bR; int kk, Kt;
        if (ktg < s1.ktn) { aR = aP1; bR = bP1; kk = (ktg << 6) + sk; Kt = s1.K; }
        else              { aR = aP2; bR = bP2; kk = ((ktg - s1.ktn) << 6) + sk; Kt = s2.K; }
        sa0 = stage8b(aR, true, kk, Kt);  sa1 = stage8b(aR, true, kk + 8, Kt);
        sb0 = stage8b(bR, bok,  kk, Kt);  sb1 = stage8b(bR, bok,  kk + 8, Kt);
    }
    *(short8v*)&As[0][sr][sk] = sa0; *(short8v*)&As[0][sr][sk + 8] = sa1;
    *(short8v*)&Bs[0][sr][sk] = sb0; *(short8v*)&Bs[0][sr][sk + 8] = sb1;
    __syncthreads();

    int cur = 0;
    for (int kt = 0; kt < nk; ++kt) {
        const bool more = (kt + 1 < nk);
        if (more) {
            const int ktg = kt0 + kt + 1;
            const unsigned short* aR; const unsigned short* bR; int kk, Kt;
            if (ktg < s1.ktn) { aR = aP1; bR = bP1; kk = (ktg << 6) + sk; Kt = s1.K; }
            else              { aR = aP2; bR = bP2; kk = ((ktg - s1.ktn) << 6) + sk; Kt = s2.K; }
            sa0 = stage8b(aR, true, kk, Kt);  sa1 = stage8b(aR, true, kk + 8, Kt);
            sb0 = stage8b(bR, bok,  kk, Kt);  sb1 = stage8b(bR, bok,  kk + 8, Kt);
        }
#pragma unroll
        for (int ks = 0; ks < 2; ++ks) {
            const int ko = ks * 32 + g8;
            short8v a0 = *(const short8v*)&As[cur][wrow + lr][ko];
            short8v a1 = *(const short8v*)&As[cur][wrow + 16 + lr][ko];
            short8v b0 = *(const short8v*)&Bs[cur][wcol + lr][ko];
            short8v b1 = *(const short8v*)&Bs[cur][wcol + 16 + lr][ko];
            acc[0][0] = __builtin_amdgcn_mfma_f32_16x16x32_bf16(a0, b0, acc[0][0], 0, 0, 0);
            acc[0][1] = __builtin_amdgcn_mfma_f32_16x16x32_bf16(a0, b1, acc[0][1], 0, 0, 0);
            acc[1][0] = __builtin_amdgcn_mfma_f32_16x16x32_bf16(a1, b0, acc[1][0], 0, 0, 0);
            acc[1][1] = __builtin_amdgcn_mfma_f32_16x16x32_bf16(a1, b1, acc[1][1], 0, 0, 0);
        }
        if (more) {
            *(short8v*)&As[cur ^ 1][sr][sk] = sa0;
            *(short8v*)&As[cur ^ 1][sr][sk + 8] = sa1;
            *(short8v*)&Bs[cur ^ 1][sr][sk] = sb0;
            *(short8v*)&Bs[cur ^ 1][sr][sk + 8] = sb1;
        }
        __syncthreads();
        cur ^= 1;
    }

    float* Cp = C + (size_t)bz * ((size_t)rowBlocks * 64) * ldc;
#pragma unroll
    for (int m = 0; m < 2; ++m)
#pragma unroll
        for (int n = 0; n < 2; ++n)
#pragma unroll
            for (int j = 0; j < 4; ++j) {
                const int r = row0 + wrow + m * 16 + g * 4 + j;
                const int c = col0 + wcol + n * 16 + lr;
                if (c < Ncols) {
                    float v = acc[m][n][j];
                    if (bias) v += bias[c];
                    Cp[(size_t)r * ldc + c] = v;
                }
            }
}

// ==== M1: att_e slabs (4096) || cvt{E_w:313, inp:157, h:16} ====
__global__ __launch_bounds__(256) void m1_atte_cvt1(
    const float* __restrict__ a_i, const float* __restrict__ f_att_w,
    float* __restrict__ pe,
    const float* __restrict__ E_w, const float* __restrict__ inp,
    const float* __restrict__ h,
    unsigned short* __restrict__ ewb, unsigned short* __restrict__ inpb,
    unsigned short* __restrict__ hb)
{
    __shared__ __align__(16) float slab[6280];
    const int bid = blockIdx.x;
    const int t = threadIdx.x;

    if (bid < 4096) {
        const int b = bid >> 4, ch = bid & 15;
        const int w = t >> 6, lane = t & 63;
        const float* gbase = a_i + ((size_t)b * DD + ch * 32) * LL;
#pragma unroll
        for (int k = 0; k < 7; ++k) {
            const int cw = k * 256 + w * 64;
            if (cw + lane < 1568)
                gl_lds16(gbase + (size_t)(cw + lane) * 4, slab + (size_t)cw * 4);
        }
        if (t < 8) slab[6272 + t] = 0.f;
        asm volatile("s_waitcnt vmcnt(0)" ::: "memory");
        __syncthreads();
        if (t < LL) {
            const float* wp = f_att_w + ch * 32;
            float e = 0.f;
#pragma unroll
            for (int d = 0; d < 32; ++d) e += slab[d * LL + t] * wp[d];
            pe[((size_t)b * 16 + ch) * LL + t] = e;
        }
    } else {
        int lb = bid - 4096;
        if      (lb < 313) cvt_body(lb, E_w, ewb, 5120000, t);
        else if (lb < 470) cvt_body(lb - 313, inp, inpb, 2560000, t);
        else               cvt_body(lb - 470, h, hb, 262144, t);
    }
}

// ==== M2: softmax (256) || emb GEMM (512) || cvt{W_ih:512, W_hh:256} ====
__global__ __launch_bounds__(256) void m2_softmax_emb_cvt2(
    const float* __restrict__ pe, const float* __restrict__ h,
    const float* __restrict__ f_att_w, const float* __restrict__ f_att_b,
    const float* __restrict__ gate_w, const float* __restrict__ gate_b,
    float* __restrict__ alpha_out, float* __restrict__ beta,
    const unsigned short* __restrict__ inpb, const unsigned short* __restrict__ ewb,
    float* __restrict__ embp,
    const float* __restrict__ W_ih, const float* __restrict__ W_hh,
    unsigned short* __restrict__ wihb, unsigned short* __restrict__ whhb)
{
    __shared__ __align__(16) unsigned char smem[36864];
    const int bid = blockIdx.x;
    const int t = threadIdx.x;
    if (bid < 256) {
        const int b = bid;
        float* red  = (float*)smem;
        float* red2 = red + 256;
        const float4 h4 = *(const float4*)(h + (size_t)b * NN + t * 4);
        const float4 w4 = *(const float4*)(f_att_w + DD + t * 4);
        const float4 g4 = *(const float4*)(gate_w + t * 4);
        float hd = h4.x * w4.x + h4.y * w4.y + h4.z * w4.z + h4.w * w4.w;
        float gd = h4.x * g4.x + h4.y * g4.y + h4.z * g4.z + h4.w * g4.w;
        red[t] = hd; red2[t] = gd;
        __syncthreads();
        for (int s = 128; s > 0; s >>= 1) {
            if (t < s) { red[t] += red[t + s]; red2[t] += red2[t + s]; }
            __syncthreads();
        }
        const float hdot = red[0];
        const float gdot = red2[0];
        __syncthreads();
        float e = -3.4e38f;
        if (t < LL) {
            const float* pp = pe + (size_t)b * 16 * LL + t;
            e = hdot + f_att_b[0];
#pragma unroll
            for (int ch = 0; ch < 16; ++ch) e += pp[ch * LL];
        }
        red[t] = e;
        __syncthreads();
        for (int s = 128; s > 0; s >>= 1) {
            if (t < s) red[t] = fmaxf(red[t], red[t + s]);
            __syncthreads();
        }
        const float mx = red[0];
        __syncthreads();
        const float ex = (t < LL) ? expf(e - mx) : 0.f;
        red[t] = ex;
        __syncthreads();
        for (int s = 128; s > 0; s >>= 1) {
            if (t < s) red[t] += red[t + s];
            __syncthreads();
        }
        const float inv = 1.f / red[0];
        if (t < LL) alpha_out[(size_t)b * LL + t] = ex * inv;
        if (t == 0) beta[b] = 1.f / (1.f + expf(-(gdot + gate_b[0])));
    } else if (bid < 768) {
        short (*As)[64][72] = (short (*)[64][72])smem;
        short (*Bs)[64][72] = (short (*)[64][72])(smem + 18432);
        const int i = bid - 256;                      // 512 = 4*8*16, nk<=10
        GSrc s1 = {inpb, KK, ewb, KK, 157, KK};
        GSrc s2 = {nullptr, 0, nullptr, 0, 0, 0};
        gemm_body(i & 3, (i >> 2) & 7, i >> 5, 4, s1, s2,
                  embp, MM, MM, 10, nullptr, As, Bs);
    } else {
        int lb = bid - 768;
        if (lb < 512) cvt_body(lb, W_ih, wihb, 8388608, t);
        else          cvt_body(lb - 512, W_hh, whhb, 4194304, t);
    }
}

// ==== M3: att_z slabs (4096) || emb reduce (512) || cvt{Lo:313,Lh:32,Lz:16} ====
__global__ __launch_bounds__(256) void m3_attz_embred_cvt3(
    const float* __restrict__ a_i, const float* __restrict__ alpha,
    const float* __restrict__ beta, unsigned short* __restrict__ zb,
    const float* __restrict__ embp, const float* __restrict__ E_b,
    float* __restrict__ emb, unsigned short* __restrict__ embb,
    const float* __restrict__ Lo_w, const float* __restrict__ Lh_w,
    const float* __restrict__ Lz_w,
    unsigned short* __restrict__ lob, unsigned short* __restrict__ lhb,
    unsigned short* __restrict__ lzb)
{
    __shared__ __align__(16) float slab[6280];
    __shared__ float al[200];
    const int bid = blockIdx.x;
    const int t = threadIdx.x;

    if (bid < 4096) {
        const int b = bid >> 4, ch = bid & 15;
        const int w = t >> 6, lane = t & 63;
        const float* gbase = a_i + ((size_t)b * DD + ch * 32) * LL;
#pragma unroll
        for (int k = 0; k < 7; ++k) {
            const int cw = k * 256 + w * 64;
            if (cw + lane < 1568)
                gl_lds16(gbase + (size_t)(cw + lane) * 4, slab + (size_t)cw * 4);
        }
        if (t < 200) al[t] = (t < LL) ? alpha[(size_t)b * LL + t] : 0.f;
        if (t < 8) slab[6272 + t] = 0.f;
        asm volatile("s_waitcnt vmcnt(0)" ::: "memory");
        __syncthreads();
        const int r = t >> 3, q = t & 7;
        const float* rowp = slab + r * LL + q * 25;
        const float* alq  = al + q * 25;
        float s = 0.f;
#pragma unroll
        for (int j = 0; j < 25; ++j) s += rowp[j] * alq[j];
        s += __shfl_xor(s, 1, 64);
        s += __shfl_xor(s, 2, 64);
        s += __shfl_xor(s, 4, 64);
        if (q == 0) zb[(size_t)b * DD + ch * 32 + r] = f2bf(beta[b] * s);
    } else if (bid < 4608) {
        const int idx = (bid - 4096) * 256 + t;       // < B*512
        const int j = idx & 511;
        float v = E_b[j];
#pragma unroll
        for (int s = 0; s < 16; ++s) v += embp[(size_t)s * (BB * 512) + idx];
        emb[idx] = v;
        embb[idx] = f2bf(v);
    } else {
        int lb = bid - 4608;
        if      (lb < 313) cvt_body(lb, Lo_w, lob, 5120000, t);
        else if (lb < 345) cvt_body(lb - 313, Lh_w, lhb, 524288, t);
        else               cvt_body(lb - 345, Lz_w, lzb, 262144, t);
    }
}

// ==== M4: gates_h (1024) || gates_e (512) || gates_z (512) || lz (256) ====
__global__ __launch_bounds__(256) void m4_gates_lz(
    const unsigned short* __restrict__ hb, const unsigned short* __restrict__ embb,
    const unsigned short* __restrict__ zb,
    const unsigned short* __restrict__ wihb, const unsigned short* __restrict__ whhb,
    float* __restrict__ gatesp,
    const unsigned short* __restrict__ lzb, float* __restrict__ dp)
{
    __shared__ __align__(16) unsigned char smem[36864];
    short (*As)[64][72] = (short (*)[64][72])smem;
    short (*Bs)[64][72] = (short (*)[64][72])(smem + 18432);
    const int bid = blockIdx.x;
    if (bid < 1024) {                                 // 4*64*4 -> slices 0..3
        GSrc s1 = {hb, NN, wihb + 512, 2048, 16, NN};
        GSrc s2 = {hb, NN, whhb, NN, 16, NN};
        gemm_body(bid & 3, (bid >> 2) & 63, bid >> 8, 4, s1, s2,
                  gatesp, 4096, 4096, 8, nullptr, As, Bs);
    } else if (bid < 1536) {                          // 4*64*2 -> slices 4..5
        const int i = bid - 1024;
        GSrc s1 = {embb, MM, wihb, 2048, 8, MM};
        GSrc s2 = {nullptr, 0, nullptr, 0, 0, 0};
        gemm_body(i & 3, (i >> 2) & 63, i >> 8, 4, s1, s2,
                  gatesp + (size_t)4 * BB * 4096, 4096, 4096, 4, nullptr, As, Bs);
    } else if (bid < 2048) {                          // slices 6..7
        const int i = bid - 1536;
        GSrc s1 = {zb, DD, wihb + 1536, 2048, 8, DD};
        GSrc s2 = {nullptr, 0, nullptr, 0, 0, 0};
        gemm_body(i & 3, (i >> 2) & 63, i >> 8, 4, s1, s2,
                  gatesp + (size_t)6 * BB * 4096, 4096, 4096, 4, nullptr, As, Bs);
    } else {
        const int i = bid - 2048;                     // 256 = 4*8*8 -> dp 0..7
        GSrc s1 = {zb, DD, lzb, DD, 8, DD};
        GSrc s2 = {nullptr, 0, nullptr, 0, 0, 0};
        gemm_body(i & 3, (i >> 2) & 7, i >> 5, 4, s1, s2,
                  dp, MM, MM, 1, nullptr, As, Bs);
    }
}

// ==== M5: LSTM cell (sums 8 gate slices) -> hn fp32 + bf16 ====
__global__ __launch_bounds__(256) void m5_lstm(
    const float* __restrict__ gatesp,
    const float* __restrict__ b_ih, const float* __restrict__ b_hh,
    const float* __restrict__ c_prev, float* __restrict__ hn, float* __restrict__ cn,
    unsigned short* __restrict__ hnb)
{
    const int idx = blockIdx.x * 256 + threadIdx.x;   // < B*1024
    const int b = idx >> 10, n = idx & 1023;
    float g[4];
#pragma unroll
    for (int gi = 0; gi < 4; ++gi) {
        const int col = gi * 1024 + n;
        const size_t o = (size_t)b * 4096 + col;
        float v = b_ih[col] + b_hh[col];
#pragma unroll
        for (int s = 0; s < 8; ++s) v += gatesp[(size_t)s * (BB * 4096) + o];
        g[gi] = v;
    }
    const float si = 1.f / (1.f + expf(-g[0]));
    const float sf = 1.f / (1.f + expf(-g[1]));
    const float so = 1.f / (1.f + expf(-g[3]));
    const float tg = tanhf(g[2]);
    const float c = c_prev[idx];
    const float cnv = sf * c + si * tg;
    const float hnv = so * tanhf(cnv);
    cn[idx] = cnv;
    hn[idx] = hnv;
    hnb[idx] = f2bf(hnv);
}

// ==== M6: lh GEMM (512, dp slices 8..23) ====
__global__ __launch_bounds__(256) void m6_lh(
    const unsigned short* __restrict__ hnb, const unsigned short* __restrict__ lhb,
    float* __restrict__ dp_hi)
{
    __shared__ __align__(16) short As[2][64][72];
    __shared__ __align__(16) short Bs[2][64][72];
    const int bid = blockIdx.x;                       // 512 = 4*8*16
    GSrc s1 = {hnb, NN, lhb, NN, 16, NN};
    GSrc s2 = {nullptr, 0, nullptr, 0, 0, 0};
    gemm_body(bid & 3, (bid >> 2) & 7, bid >> 5, 4, s1, s2,
              dp_hi, MM, MM, 1, nullptr, As, Bs);
}

// ==== M7: build deep -> bf16 ====
__global__ __launch_bounds__(256) void m7_deep(
    const float* __restrict__ emb, const float* __restrict__ dp,
    const float* __restrict__ Lh_b, const float* __restrict__ Lz_b,
    unsigned short* __restrict__ deepb)
{
    const int idx = blockIdx.x * 256 + threadIdx.x;   // < B*512
    const int j = idx & 511;
    float v = emb[idx] + Lh_b[j] + Lz_b[j];
#pragma unroll
    for (int s = 0; s < 24; ++s) v += dp[(size_t)s * (BB * 512) + idx];
    deepb[idx] = f2bf(v);
}

// ==== M8: p_yt GEMM (628) ====
__global__ __launch_bounds__(256) void m8_pyt(
    const unsigned short* __restrict__ deepb, const unsigned short* __restrict__ lob,
    const float* __restrict__ Lo_b, float* __restrict__ out)
{
    __shared__ __align__(16) short As[2][64][72];
    __shared__ __align__(16) short Bs[2][64][72];
    const int bid = blockIdx.x;                       // 628 = 4*157
    GSrc s1 = {deepb, MM, lob, MM, 8, MM};
    GSrc s2 = {nullptr, 0, nullptr, 0, 0, 0};
    gemm_body(bid & 3, bid >> 2, 0, 4, s1, s2,
              out, KK, KK, 8, Lo_b, As, Bs);
}

extern "C" void kernel_launch(void* const* d_in, const int* in_sizes, int n_in,
                              void* d_out, int out_size, void* d_ws, size_t ws_size,
                              hipStream_t stream)
{
    const float* a_i     = (const float*)d_in[0];
    const float* inp     = (const float*)d_in[1];
    const float* hn_prev = (const float*)d_in[2];
    const float* cn_prev = (const float*)d_in[3];
    const float* f_att_w = (const float*)d_in[4];
    const float* f_att_b = (const float*)d_in[5];
    const float* gate_w  = (const float*)d_in[6];
    const float* gate_b  = (const float*)d_in[7];
    const float* E_w     = (const float*)d_in[8];
    const float* E_b     = (const float*)d_in[9];
    const float* W_ih    = (const float*)d_in[10];
    const float* W_hh    = (const float*)d_in[11];
    const float* b_ih    = (const float*)d_in[12];
    const float* b_hh    = (const float*)d_in[13];
    const float* Lh_w    = (const float*)d_in[14];
    const float* Lh_b    = (const float*)d_in[15];
    const float* Lz_w    = (const float*)d_in[16];
    const float* Lz_b    = (const float*)d_in[17];
    const float* Lo_w    = (const float*)d_in[18];
    const float* Lo_b    = (const float*)d_in[19];

    float* out = (float*)d_out;
    float* ws  = (float*)d_ws;

    float* PE     = ws + OFF_PE;
    float* BETA   = ws + OFF_BETA;
    float* EMB    = ws + OFF_EMB;
    float* EMBP   = ws + OFF_EMBP;
    float* GATESP = ws + OFF_GATESP;
    float* DP     = ws + OFF_DP;
    unsigned short* EWB   = (unsigned short*)(ws + OFF_EWB);
    unsigned short* WIHB  = (unsigned short*)(ws + OFF_WIHB);
    unsigned short* WHHB  = (unsigned short*)(ws + OFF_WHHB);
    unsigned short* LHB   = (unsigned short*)(ws + OFF_LHB);
    unsigned short* LZB   = (unsigned short*)(ws + OFF_LZB);
    unsigned short* LOB   = (unsigned short*)(ws + OFF_LOB);
    unsigned short* INPB  = (unsigned short*)(ws + OFF_INPB);
    unsigned short* HB    = (unsigned short*)(ws + OFF_HB);
    unsigned short* ZB    = (unsigned short*)(ws + OFF_ZB);
    unsigned short* EMBB  = (unsigned short*)(ws + OFF_EMBB);
    unsigned short* DEEPB = (unsigned short*)(ws + OFF_DEEPB);
    unsigned short* HNB   = (unsigned short*)(ws + OFF_HNB);

    // M1: att_e || cvt{E_w, inp, h}            (4096 + 486)
    m1_atte_cvt1<<<4582, 256, 0, stream>>>(a_i, f_att_w, PE,
                                           E_w, inp, hn_prev, EWB, INPB, HB);

    // M2: softmax || emb GEMM || cvt{W_ih, W_hh}  (256 + 512 + 768)
    m2_softmax_emb_cvt2<<<1536, 256, 0, stream>>>(
        PE, hn_prev, f_att_w, f_att_b, gate_w, gate_b,
        out + OUT_AL, BETA, INPB, EWB, EMBP, W_ih, W_hh, WIHB, WHHB);

    // M3: att_z || emb reduce || cvt{Lo, Lh, Lz}  (4096 + 512 + 361)
    m3_attz_embred_cvt3<<<4969, 256, 0, stream>>>(
        a_i, out + OUT_AL, BETA, ZB, EMBP, E_b, EMB, EMBB,
        Lo_w, Lh_w, Lz_w, LOB, LHB, LZB);

    // M4: gates_h || gates_e || gates_z || lz  (1024+512+512+256)
    m4_gates_lz<<<2304, 256, 0, stream>>>(HB, EMBB, ZB, WIHB, WHHB,
                                          GATESP, LZB, DP);

    // M5: LSTM cell
    m5_lstm<<<1024, 256, 0, stream>>>(GATESP, b_ih, b_hh, cn_prev,
                                      out + OUT_HN, out + OUT_CN, HNB);

    // M6: hn@Lh_w^T (dp slices 8..23)
    m6_lh<<<512, 256, 0, stream>>>(HNB, LHB, DP + (size_t)8 * BB * 512);

    // M7: deep = emb + sum(dp) + biases -> bf16
    m7_deep<<<512, 256, 0, stream>>>(EMB, DP, Lh_b, Lz_b, DEEPB);

    // M8: p_yt = deep @ Lo_w^T + Lo_b
    m8_pyt<<<628, 256, 0, stream>>>(DEEPB, LOB, Lo_b, out + OUT_PY);
}